// Round 4
// baseline (430.306 us; speedup 1.0000x reference)
//
#include <hip/hip_runtime.h>

// ConvLSTM2D via MFMA implicit-GEMM. B=8,T=16,H=W=64,Cin=32,F=64,3x3 SAME.
// Round 11: group-of-3 K-loop. Post-mortem of R7-R10: R7 (barrier-free,
// wave-private B) ran at the SUM of its pipes (LDS 1129 + L2 585 + MFMA 621
// ~= 2335 cyc/iter ~= measured 2311); R9/R10 cut pipe demand (shared ring:
// 941+292+621) but their per-iteration barriers re-serialized the CU into
// lockstep [read burst | MFMA burst] rounds, landing at the same ~2300.
// Fix needs BOTH low demand AND scheduling freedom: shared P=6 ring (96 KB)
// with ONE __syncthreads per 3 k-steps. Within a group: 24 ds_read_b128 +
// 48 MFMA + 6 DMA issues, zero sync ops -- the compiler interleaves reads
// with MFMAs across iterations (the only latency-hiding available at
// 2 waves/SIMD). __syncthreads' built-in vmcnt(0) drain IS the slot
// certification: next-group DMAs are issued at group start, in flight for
// ~2000 cyc >> L2 latency, so the drain doesn't stall. Barriers: 27 -> 10
// per step. No manual vmcnt / sched_barrier / setprio -- they pin the
// schedule, the opposite of what this structure needs.
//
// Structure: 128-px blocks (16x8, 512 thr, 8 waves), waves = 2(px-half) x
// 4(n-group); ring slot = 16 KB (256ch x 32k bf16), DMA'd once per block
// per k-step (wave w stages nt {w,w+8}). A halos in LDS bf16 (pad 40/72).
// h ping-pongs bf16 in ws; c fp32 in d_out. LDS 136 KB -> 1 block/CU.

#define TSTEPS 16

typedef short bf16x8 __attribute__((ext_vector_type(8)));
typedef float f32x4 __attribute__((ext_vector_type(4)));
typedef unsigned int __attribute__((address_space(1))) gu32;
typedef unsigned int __attribute__((address_space(3))) lu32;

__device__ __forceinline__ float hsig(float x) {
    return fminf(fmaxf((x + 3.0f) * (1.0f / 6.0f), 0.0f), 1.0f);
}

__device__ __forceinline__ unsigned short f2bf(float f) {
    union { float f; unsigned int u; } v; v.f = f;
    unsigned int r = v.u + 0x7fffu + ((v.u >> 16) & 1u);  // RNE
    return (unsigned short)(r >> 16);
}

// ---- weight prepack: Wg(3,3,32,256), Ug(3,3,64,256) fp32 -> bf16 B-frags ----
__global__ __launch_bounds__(256)
void prepack_w(const float* __restrict__ Wg, const float* __restrict__ Ug,
               unsigned short* __restrict__ out)
{
    int idx = blockIdx.x * 256 + threadIdx.x;   // 27*16*64 = 27648
    if (idx >= 27648) return;
    int lane = idx & 63;
    int nt   = (idx >> 6) & 15;
    int s    = idx >> 10;
    int col = lane & 15, quad = lane >> 4;
    int n = nt * 16 + col;
    int k0 = quad * 8;
    const float* src;
    if (s < 9) {
        src = Wg + ((size_t)s * 32 + k0) * 256 + n;
    } else {
        int ss = s - 9; int tap = ss >> 1; int half = ss & 1;
        src = Ug + ((size_t)tap * 64 + half * 32 + k0) * 256 + n;
    }
    unsigned short tmp[8];
    #pragma unroll
    for (int j = 0; j < 8; ++j) tmp[j] = f2bf(src[(size_t)j * 256]);
    *(uint4*)(out + (size_t)idx * 8) = *(uint4*)tmp;
}

// ---- one ConvLSTM step (NS = 9 for t==0, 27 otherwise) ----
template<int NS>
__global__ __launch_bounds__(512)
__attribute__((amdgpu_waves_per_eu(2, 2)))
void convlstm_step(const float* __restrict__ x,       // (B,T,64,64,32) fp32
                   const unsigned short* __restrict__ wpk,
                   const float* __restrict__ bias,    // (256)
                   const unsigned short* __restrict__ h_in, // bf16 (B,64,64,64)
                   float* __restrict__ c_st,          // fp32 (B,64,64,64) = d_out
                   unsigned short* __restrict__ h_out,// bf16 ping
                   int t, int is_last)
{
    constexpr bool HP = (NS == 27);
    constexpr int  P  = 6;   // B ring depth (2 groups of 3 k-steps)

    // tile: 16 rows (y) x 8 cols (x) = 128 px; halo 18x10 = 180 px
    __shared__ __align__(16) unsigned short xs_s[180 * 40];           // 14.4 KB
    __shared__ __align__(16) unsigned short hs_s[HP ? 180 * 72 : 8];  // 25.9 KB
    __shared__ __align__(16) unsigned short bring[P * 16 * 512];      // 96.0 KB

    const int tid = threadIdx.x;
    const int gx0 = blockIdx.x * 8;
    const int gy0 = blockIdx.y * 16;
    const int b   = blockIdx.z;

    const int lane  = tid & 63;
    const int w     = tid >> 6;        // wave 0..7
    const int pxgrp = w >> 2;          // 0: rows 0-7, 1: rows 8-15
    const int ngrp  = w & 3;           // n-group: nt in {ngrp, ngrp+4, ngrp+8, ngrp+12}
    const int quad  = lane >> 4;
    const int m     = lane & 15;
    const int ch    = ngrp * 16 + m;   // output channel 0..63

    // ---- B DMA: wave w stages nt {w, w+8} for k-step s into slot s%P ----
    auto issueDMA = [&](int s) {
        int slot = s % P;
        #pragma unroll
        for (int g = 0; g < 2; ++g) {
            int nt = w + 8 * g;
            const unsigned short* gp = wpk + ((size_t)(s * 16 + nt) * 64 + lane) * 8;
            unsigned short* lp = bring + ((size_t)slot * 16 + nt) * 512;  // uniform
            __builtin_amdgcn_global_load_lds((const gu32*)gp, (lu32*)lp, 16, 0, 0);
        }
    };

    // ---- prologue: fill group-0 slots; staging barrier certifies them ----
    issueDMA(0);
    issueDMA(1);
    issueDMA(2);

    // ---- stage x halo (fp32 -> bf16) ----
    {
        const float* xt = x + (((size_t)b * TSTEPS + t) * (size_t)(64 * 64 * 32));
        #pragma unroll 3
        for (int idx = tid; idx < 180 * 8; idx += 512) {
            int pix = idx >> 3, q = idx & 7;
            int iy = pix / 10, ix = pix - iy * 10;
            int gy = gy0 + iy - 1, gx = gx0 + ix - 1;
            unsigned short o[4] = {0, 0, 0, 0};
            if ((unsigned)gy < 64u && (unsigned)gx < 64u) {
                float4 v = *(const float4*)(xt + ((size_t)(gy * 64 + gx) * 32) + q * 4);
                o[0] = f2bf(v.x); o[1] = f2bf(v.y); o[2] = f2bf(v.z); o[3] = f2bf(v.w);
            }
            *(ushort4*)(xs_s + pix * 40 + q * 4) = *(ushort4*)o;
        }
    }
    // ---- stage h halo (bf16 copy) ----
    if constexpr (HP) {
        const unsigned short* hb = h_in + ((size_t)b * (64 * 64 * 64));
        #pragma unroll 3
        for (int idx = tid; idx < 180 * 8; idx += 512) {
            int pix = idx >> 3, q = idx & 7;
            int iy = pix / 10, ix = pix - iy * 10;
            int gy = gy0 + iy - 1, gx = gx0 + ix - 1;
            uint4 v = make_uint4(0u, 0u, 0u, 0u);
            if ((unsigned)gy < 64u && (unsigned)gx < 64u)
                v = *(const uint4*)(hb + ((size_t)(gy * 64 + gx) * 64) + q * 8);
            *(uint4*)(hs_s + pix * 72 + q * 8) = v;
        }
    }
    __syncthreads();   // staging + ring slots 0-2 visible (full vmcnt drain)

    int xb[4], hb_[4];
    #pragma unroll
    for (int mt = 0; mt < 4; ++mt) {
        int p = mt * 16 + m;
        int row = pxgrp * 8 + (p >> 3);
        int cc  = p & 7;
        xb[mt]  = (row * 10 + cc) * 40 + quad * 8;
        hb_[mt] = (row * 10 + cc) * 72 + quad * 8;
    }

    // acc init = bias
    f32x4 acc[4][4];   // [mt][gate]
    #pragma unroll
    for (int g = 0; g < 4; ++g) {
        float bv = bias[g * 64 + ch];
        f32x4 bi = (f32x4){bv, bv, bv, bv};
        #pragma unroll
        for (int mt = 0; mt < 4; ++mt) acc[mt][g] = bi;
    }

    // ---- K-loop: 3 k-steps per barrier, free scheduling within a group ----
    #pragma unroll
    for (int g0 = 0; g0 < NS; g0 += 3) {
        // stage next group's slots (other ring half; consumed-and-published
        // two barriers ago, so overwrite is safe)
        if (g0 + 3 < NS) { issueDMA(g0 + 3); issueDMA(g0 + 4); issueDMA(g0 + 5); }

        #pragma unroll
        for (int j = 0; j < 3; ++j) {
            const int s = g0 + j;           // compile-time
            const int slot = s % P;

            bf16x8 bfr[4];
            #pragma unroll
            for (int g = 0; g < 4; ++g)
                bfr[g] = *(const bf16x8*)(bring + ((size_t)slot * 16 + (ngrp + 4 * g)) * 512 + lane * 8);

            bf16x8 a[4];
            if (s < 9) {
                int taplin = (s / 3) * 10 + (s % 3);
                #pragma unroll
                for (int mt = 0; mt < 4; ++mt)
                    a[mt] = *(const bf16x8*)(xs_s + xb[mt] + taplin * 40);
            } else {
                int ss = s - 9, tap = ss >> 1, half = ss & 1;
                int taplin = (tap / 3) * 10 + (tap % 3);
                #pragma unroll
                for (int mt = 0; mt < 4; ++mt)
                    a[mt] = *(const bf16x8*)(hs_s + hb_[mt] + taplin * 72 + half * 32);
            }

            #pragma unroll
            for (int g = 0; g < 4; ++g)
                #pragma unroll
                for (int mt = 0; mt < 4; ++mt)
                    acc[mt][g] = __builtin_amdgcn_mfma_f32_16x16x32_bf16(a[mt], bfr[g], acc[mt][g], 0, 0, 0);
        }

        // group boundary: drains the 6 in-flight DMAs (vmcnt(0)) and
        // publishes next group's slots to all waves
        __syncthreads();
    }

    // ---- epilogue: gates + state update ----
    // C/D layout: col = lane&15 (channel), row = quad*4 + r (pixel)
    #pragma unroll
    for (int mt = 0; mt < 4; ++mt) {
        #pragma unroll
        for (int r = 0; r < 4; ++r) {
            int p = mt * 16 + quad * 4 + r;
            int py = pxgrp * 8 + (p >> 3), px = p & 7;
            size_t gidx = (((size_t)b * 64 + (gy0 + py)) * 64 + (gx0 + px)) * 64 + ch;
            float zi = acc[mt][0][r];
            float zf = acc[mt][1][r];
            float zc = acc[mt][2][r];
            float zo = acc[mt][3][r];
            float c_prev = HP ? c_st[gidx] : 0.0f;
            float cn = hsig(zf) * c_prev + hsig(zi) * fmaxf(zc, 0.0f);
            float hn = hsig(zo) * fmaxf(cn, 0.0f);
            if (is_last) {
                c_st[gidx] = hn;            // d_out gets final h (fp32)
            } else {
                c_st[gidx] = cn;
                h_out[gidx] = f2bf(hn);
            }
        }
    }
}

extern "C" void kernel_launch(void* const* d_in, const int* in_sizes, int n_in,
                              void* d_out, int out_size, void* d_ws, size_t ws_size,
                              hipStream_t stream) {
    const float* x  = (const float*)d_in[0];
    const float* Wg = (const float*)d_in[1];
    const float* Ug = (const float*)d_in[2];
    const float* bs = (const float*)d_in[3];

    // ws layout: [packed weights 442368 B][h0 bf16 4 MB][h1 bf16 4 MB]
    unsigned short* wpk = (unsigned short*)d_ws;
    unsigned short* h0  = (unsigned short*)((char*)d_ws + 27 * 16 * 64 * 8 * 2);
    unsigned short* h1  = h0 + (size_t)8 * 64 * 64 * 64;
    float* cS = (float*)d_out;

    prepack_w<<<108, 256, 0, stream>>>(Wg, Ug, wpk);

    dim3 grid(8, 4, 8);   // 8 x-tiles, 4 y-tiles (16 rows each), 8 batches
    dim3 block(512);
    for (int t = 0; t < TSTEPS; ++t) {
        const unsigned short* hin = (t == 0) ? h0 : ((t & 1) ? h0 : h1);
        unsigned short* hout = (t & 1) ? h1 : h0;
        if (t == 0) {
            convlstm_step<9><<<grid, block, 0, stream>>>(x, wpk, bs, hin, cS, hout, t, 0);
        } else {
            convlstm_step<27><<<grid, block, 0, stream>>>(x, wpk, bs, hin, cS, hout,
                                                          t, (t == TSTEPS - 1) ? 1 : 0);
        }
    }
}